// Round 9
// baseline (11952.291 us; speedup 1.0000x reference)
//
#include <hip/hip_runtime.h>
#include <hip/hip_bf16.h>

#define NIN 32
#define NHID 128
#define NOUT 16
#define NIN1 160   // NIN+NHID
#define SEQT 512
#define NB 256

// ---------------- shared math helpers ----------------

// Knots: t_m = -8.8 + 1.6*m (G=5, K=3, range [-4,4]); verified rounds 3-8 PASS.
__device__ __forceinline__ void spline_feat(float c, float* out4, int* jst) {
    const float t0 = -8.8f, hh = 1.6f;
    int m0 = (int)floorf((c - t0) / hh);
    bool valid = (m0 >= 0) && (m0 <= 10);
    float v0 = 1.f, v1 = 0.f, v2 = 0.f, v3 = 0.f;
    #pragma unroll
    for (int d = 1; d <= 3; ++d) {
        float inv = 1.f / (d * hh);
        float nv[4];
        float pv[4] = {v0, v1, v2, v3};
        #pragma unroll
        for (int r = 3; r >= 0; --r) {
            if (r > d) { nv[r] = 0.f; continue; }
            int m = m0 - d + r;
            float tm = t0 + hh * (float)m;
            float left  = (r >= 1) ? pv[r-1] : 0.f;
            float right = (r <= d-1) ? pv[r] : 0.f;
            nv[r] = ((c - tm) * left + (tm + hh * (float)(d+1) - c) * right) * inv;
        }
        v0 = nv[0]; v1 = nv[1]; v2 = nv[2]; v3 = nv[3];
    }
    float v[4] = {v0, v1, v2, v3};
    int jb = m0 - 3;
    int js = jb < 0 ? 0 : (jb > 4 ? 4 : jb);
    int sh = js - jb;
    #pragma unroll
    for (int r = 0; r < 4; ++r) {
        int rs = r + sh;
        out4[r] = (valid && rs >= 0 && rs <= 3) ? v[rs] : 0.f;
    }
    *jst = js;
}

__device__ __forceinline__ float fsilu(float c) {
    return c * __builtin_amdgcn_rcpf(1.f + __expf(-c));
}

__device__ __forceinline__ unsigned RL(unsigned v, int lane) {
    return (unsigned)__builtin_amdgcn_readlane((int)v, lane);
}

// ---------------- f16 helpers (kan_reg) ----------------
typedef _Float16 h2 __attribute__((ext_vector_type(2)));

__device__ __forceinline__ unsigned pk2(float a, float b) {
    return __builtin_bit_cast(unsigned, __builtin_amdgcn_cvt_pkrtz(a, b));
}

#if defined(__has_builtin)
#if __has_builtin(__builtin_amdgcn_fdot2)
#define HAVE_FDOT2 1
#endif
#endif
#ifndef HAVE_FDOT2
#define HAVE_FDOT2 0
#endif

#if HAVE_FDOT2
__device__ __forceinline__ float dot2h(unsigned a, unsigned b, float c) {
    return __builtin_amdgcn_fdot2(__builtin_bit_cast(h2, a),
                                  __builtin_bit_cast(h2, b), c, false);
}
#else
__device__ __forceinline__ float dot2h(unsigned a, unsigned b, float c) {
    h2 ha = __builtin_bit_cast(h2, a), hb = __builtin_bit_cast(h2, b);
    // f16->f32 cvt + fma fuses to v_fma_mix_f32 on gfx9+
    return fmaf((float)ha[1], (float)hb[1], fmaf((float)ha[0], (float)hb[0], c));
}
#endif

// ---------------- bf16 helpers (kan_safe, r5-verbatim) ----------------
__device__ __forceinline__ unsigned int f2bfbits(float f) {
    unsigned int u = __float_as_uint(f);
    return (u + 0x7fffu + ((u >> 16) & 1u)) >> 16;
}
__device__ __forceinline__ unsigned int packbf(float lo, float hi) {
    return f2bfbits(lo) | (f2bfbits(hi) << 16);
}
__device__ __forceinline__ float dot2w(unsigned int a, unsigned int b, float c) {
    float alo = __uint_as_float(a << 16), ahi = __uint_as_float(a & 0xffff0000u);
    float blo = __uint_as_float(b << 16), bhi = __uint_as_float(b & 0xffff0000u);
    return __builtin_fmaf(ahi, bhi, __builtin_fmaf(alo, blo, c));
}
__device__ __forceinline__ void feat_record(float c, uint4* pk, float* sil) {
    *sil = fsilu(c);
    float b4[4]; int js;
    spline_feat(c, b4, &js);
    float e[8];
    #pragma unroll
    for (int k = 0; k < 8; ++k) {
        int d = k - js;
        e[k] = (d >= 0 && d < 4) ? b4[d] : 0.f;
    }
    pk->x = packbf(e[0], e[1]); pk->y = packbf(e[2], e[3]);
    pk->z = packbf(e[4], e[5]); pk->w = packbf(e[6], e[7]);
}

// =================================================================
// kan_reg: 256 threads -> 256-VGPR budget (allocator's 2-block/CU rule,
// r4-r8 + m97 evidence). 2 segs x 128 o; per seg: 46 i in registers
// (23 pairs, f16-packed, sp1 folded), 34 i in LDS, 0 streamed.
// =================================================================

// pool layout (uint indices)
#define PW 0        // Wc: 68 slots x 128 o x uint4     -> 34816 uints
#define PS 34816    // sbp: 34 pair-slots x 128 o       ->  4352
#define PF 39168    // feat: 2 segs x 80 rec x 4 uints  ->   640
#define PP 39808    // silp: 160 f16 = 80 uints         ->    80
#define PR 39888    // red: 2 x 128 f32                 ->   256
#define PTOT 40144  // 160,576 B <= 163,840

#define R23(X) X(0) X(1) X(2) X(3) X(4) X(5) X(6) X(7) X(8) X(9) X(10) X(11) \
               X(12) X(13) X(14) X(15) X(16) X(17) X(18) X(19) X(20) X(21) X(22)
#define L9(X)  X(0) X(1) X(2) X(3) X(4) X(5) X(6) X(7) X(8)
#define L8(X)  X(9) X(10) X(11) X(12) X(13) X(14) X(15) X(16)

// feature component fetch, compile-time f: vA covers seg-records 0..63,
// vB covers 64..79
#define CF(f)  RL(((f)&3)==0 ? vA.x : ((f)&3)==1 ? vA.y : ((f)&3)==2 ? vA.z : vA.w, (f)>>2)
#define CFB(f) RL((((f)&1)==0) ? vB.x : vB.y, (f)>>1)

#define MAC4A(r, W) { \
    ac0 = dot2h(CF(4*(r)+0), (W).x, ac0); ac1 = dot2h(CF(4*(r)+1), (W).y, ac1); \
    ac2 = dot2h(CF(4*(r)+2), (W).z, ac2); ac3 = dot2h(CF(4*(r)+3), (W).w, ac3); }
#define MAC4B(r, W) { \
    ac0 = dot2h(CFB(4*((r)-64)+0), (W).x, ac0); ac1 = dot2h(CFB(4*((r)-64)+1), (W).y, ac1); \
    ac2 = dot2h(CFB(4*((r)-64)+2), (W).z, ac2); ac3 = dot2h(CFB(4*((r)-64)+3), (W).w, ac3); }

__global__ void __launch_bounds__(256)
kan_reg(const float* __restrict__ x,
        const float* __restrict__ coef1,
        const float* __restrict__ sb1,
        const float* __restrict__ sp1,
        const float* __restrict__ coef2,
        const float* __restrict__ sb2,
        const float* __restrict__ sp2,
        float* __restrict__ out)
{
    __shared__ __align__(16) unsigned pool[PTOT];
    float* redf = (float*)&pool[PR];

    const int tid   = threadIdx.x;
    const int b     = blockIdx.x;
    const int o     = tid & 127;
    const int seg   = tid >> 7;          // 0..1 (wave-uniform)
    const int lane  = tid & 63;
    const int ibase = seg * 80;

    // ---- LDS weights: 34 i per seg (seg-records 46..79) ----
    for (int p = tid; p < 68 * 128; p += 256) {
        int s = p >> 7, oo = p & 127;
        int sg = s >= 34, li = s - 34 * sg;
        int i = sg * 80 + 46 + li;
        const float4* cp = (const float4*)(coef1 + ((size_t)i * 128 + oo) * 8);
        float sp = sp1[i * 128 + oo];
        float4 a = cp[0], c = cp[1];
        *(uint4*)&pool[PW + p * 4] =
            make_uint4(pk2(sp * a.x, sp * a.y), pk2(sp * a.z, sp * a.w),
                       pk2(sp * c.x, sp * c.y), pk2(sp * c.z, sp * c.w));
    }
    for (int p = tid; p < 34 * 128; p += 256) {
        int q = p >> 7, oo = p & 127;
        int sg = q >= 17, qq = q - 17 * sg;
        int iA = sg * 80 + 46 + 2 * qq;
        pool[PS + p] = pk2(sb1[iA * 128 + oo], sb1[(iA + 1) * 128 + oo]);
    }

    // ---- register weights: 23 pairs per (seg,o), f16, sp1 folded ----
#define DECLP(p) uint4 wA##p, wB##p; unsigned sbw##p;
    R23(DECLP)
#undef DECLP
#define WINIT(p) { \
    int iA = ibase + 2 * (p); \
    size_t ba = ((size_t)iA * 128 + o) * 8; \
    const float4* ca = (const float4*)(coef1 + ba); \
    const float4* cb = (const float4*)(coef1 + ba + 1024); \
    float sA = sp1[iA * 128 + o], sB = sp1[iA * 128 + 128 + o]; \
    float4 a0 = ca[0], a1 = ca[1], b0 = cb[0], b1 = cb[1]; \
    wA##p = make_uint4(pk2(sA * a0.x, sA * a0.y), pk2(sA * a0.z, sA * a0.w), \
                       pk2(sA * a1.x, sA * a1.y), pk2(sA * a1.z, sA * a1.w)); \
    wB##p = make_uint4(pk2(sB * b0.x, sB * b0.y), pk2(sB * b0.z, sB * b0.w), \
                       pk2(sB * b1.x, sB * b1.y), pk2(sB * b1.z, sB * b1.w)); \
    sbw##p = pk2(sb1[iA * 128 + o], sb1[iA * 128 + 128 + o]); }
    R23(WINIT)
#undef WINIT

    redf[tid] = 0.f;                       // h0 = 0 (exactly 256 floats)
    float xv = (tid < NIN) ? x[(size_t)b * SEQT * NIN + tid] : 0.f;
    __syncthreads();

    for (int t = 0; t < SEQT; ++t) {
        // ---- phase 1: f16 features (basis + silu) for all 160 inputs ----
        if (tid < NIN1) {
            float c;
            if (tid < NIN) c = xv;
            else { int hi = tid - NIN; c = redf[hi] + redf[128 + hi]; }
            float sil = fsilu(c);
            float b4[4]; int js;
            spline_feat(c, b4, &js);
            float e[8];
            #pragma unroll
            for (int k = 0; k < 8; ++k) {
                int d = k - js;
                e[k] = (d >= 0 && d < 4) ? b4[d] : 0.f;
            }
            int sg = tid >= 80, r = tid - 80 * sg;
            *(uint4*)&pool[PF + sg * 320 + r * 4] =
                make_uint4(pk2(e[0], e[1]), pk2(e[2], e[3]),
                           pk2(e[4], e[5]), pk2(e[6], e[7]));
            ((unsigned short*)&pool[PP])[tid] = (unsigned short)(pk2(sil, 0.f) & 0xffffu);
        }
        if (tid < NIN) {                   // prefetch next x
            int tn = (t + 1 < SEQT) ? (t + 1) : t;
            xv = x[((size_t)b * SEQT + tn) * NIN + tid];
        }
        __syncthreads();

        // ---- phase 2: 3 LDS feature fetches, readlane->SGPR, dot2 ----
        uint4 vA = *(const uint4*)&pool[PF + seg * 320 + lane * 4];      // rec 0..63
        uint2 vB = *(const uint2*)&pool[PF + seg * 320 + 256 + lane * 2];// rec 64..79 (lanes<32)
        unsigned vS = pool[PP + seg * 40 + (lane < 40 ? lane : 0)];      // silu pairs

        float ac0 = 0.f, ac1 = 0.f, ac2 = 0.f, ac3 = 0.f;
#define DOTP(p) { MAC4A(2*(p), wA##p); MAC4A(2*(p)+1, wB##p); \
                  ac0 = dot2h(RL(vS, (p)), sbw##p, ac0); }
        R23(DOTP)
#undef DOTP
#define DOTLA(q) { int s0 = ((seg * 34 + 2 * (q)) << 7) + o; \
    uint4 wa = *(const uint4*)&pool[PW + s0 * 4]; \
    uint4 wb = *(const uint4*)&pool[PW + (s0 + 128) * 4]; \
    unsigned sbq = pool[PS + ((seg * 17 + (q)) << 7) + o]; \
    MAC4A(46 + 2*(q), wa); MAC4A(47 + 2*(q), wb); \
    ac0 = dot2h(RL(vS, 23 + (q)), sbq, ac0); }
        L9(DOTLA)
#undef DOTLA
#define DOTLB(q) { int s0 = ((seg * 34 + 2 * (q)) << 7) + o; \
    uint4 wa = *(const uint4*)&pool[PW + s0 * 4]; \
    uint4 wb = *(const uint4*)&pool[PW + (s0 + 128) * 4]; \
    unsigned sbq = pool[PS + ((seg * 17 + (q)) << 7) + o]; \
    MAC4B(46 + 2*(q), wa); MAC4B(47 + 2*(q), wb); \
    ac0 = dot2h(RL(vS, 23 + (q)), sbq, ac0); }
        L8(DOTLB)
#undef DOTLB
        redf[seg * 128 + o] = (ac0 + ac1) + (ac2 + ac3);
        __syncthreads();
    }

    // ---- layer 2 on final h only (fp32; verified rounds 3-8) ----
    float* Hf = (float*)pool;              // alias dead weight region: [128][9]
    if (tid < NHID) {
        float c = redf[tid] + redf[128 + tid];
        float sil = fsilu(c);
        float b4[4]; int js;
        spline_feat(c, b4, &js);
        #pragma unroll
        for (int k = 0; k < 8; ++k) {
            int d = k - js;
            Hf[tid * 9 + k] = (d >= 0 && d < 4) ? b4[d] : 0.f;
        }
        Hf[tid * 9 + 8] = sil;
    }
    __syncthreads();
    if (tid < 128) {
        int o2 = tid & 15, isg = tid >> 4;
        float acc = 0.f;
        for (int q = 0; q < 16; ++q) {
            int i = isg * 16 + q;
            const float* c2 = coef2 + (size_t)(i * NOUT + o2) * 8;
            float s = 0.f;
            #pragma unroll
            for (int k = 0; k < 8; ++k) s += Hf[i * 9 + k] * c2[k];
            acc += Hf[i * 9 + 8] * sb2[i * NOUT + o2] + sp2[i * NOUT + o2] * s;
        }
        redf[tid] = acc;
    }
    __syncthreads();
    if (tid < NOUT) {
        float a = 0.f;
        #pragma unroll
        for (int g = 0; g < 8; ++g) a += redf[g * 16 + tid];
        out[(size_t)b * NOUT + tid] = a;
    }
}

// ============ SAFE kernel: round-5 verbatim (known 1063 us, passed) ============
#define SEGI 40
#define R20(X) X(0) X(1) X(2) X(3) X(4) X(5) X(6) X(7) X(8) X(9) \
               X(10) X(11) X(12) X(13) X(14) X(15) X(16) X(17) X(18) X(19)

__global__ void __launch_bounds__(512)
kan_safe(const float* __restrict__ x,
         const float* __restrict__ coef1,
         const float* __restrict__ sb1,
         const float* __restrict__ sp1,
         const float* __restrict__ coef2,
         const float* __restrict__ sb2,
         const float* __restrict__ sp2,
         float* __restrict__ out)
{
    __shared__ __align__(16) unsigned int Fb[NIN1][4];
    __shared__ float Fsil[NIN1];
    __shared__ float red[4][NHID];
    __shared__ float Hf[NHID][9];

    const int tid  = threadIdx.x;
    const int b    = blockIdx.x;
    const int o    = tid & 127;
    const int seg  = tid >> 7;
    const int i0   = seg * SEGI;
    const int lane = tid & 63;

#define DECLP(p) uint4 wA##p, wB##p; unsigned int sbp##p;
    R20(DECLP)
#undef DECLP
#define INITP(p) { \
    const int iA = i0 + 2 * (p), iB = i0 + 2 * (p) + 1; \
    const float4* ca = (const float4*)(coef1 + (size_t)(iA * NHID + o) * 8); \
    const float4* cb = (const float4*)(coef1 + (size_t)(iB * NHID + o) * 8); \
    float spA = sp1[iA * NHID + o], spB = sp1[iB * NHID + o]; \
    float4 a0 = ca[0], a1 = ca[1], b0v = cb[0], b1v = cb[1]; \
    wA##p = make_uint4(packbf(spA * a0.x, spA * a0.y), packbf(spA * a0.z, spA * a0.w), \
                       packbf(spA * a1.x, spA * a1.y), packbf(spA * a1.z, spA * a1.w)); \
    wB##p = make_uint4(packbf(spB * b0v.x, spB * b0v.y), packbf(spB * b0v.z, spB * b0v.w), \
                       packbf(spB * b1v.x, spB * b1v.y), packbf(spB * b1v.z, spB * b1v.w)); \
    sbp##p = packbf(sb1[iA * NHID + o], sb1[iB * NHID + o]); }
    R20(INITP)
#undef INITP

    ((float*)red)[tid] = 0.f;
    float xv = (tid < NIN) ? x[(size_t)b * SEQT * NIN + tid] : 0.f;
    __syncthreads();

    for (int t = 0; t < SEQT; ++t) {
        if (tid < NIN1) {
            float c;
            if (tid < NIN) c = xv;
            else {
                int hi = tid - NIN;
                c = (red[0][hi] + red[1][hi]) + (red[2][hi] + red[3][hi]);
            }
            uint4 pk; float sil;
            feat_record(c, &pk, &sil);
            *(uint4*)&Fb[tid][0] = pk;
            Fsil[tid] = sil;
        }
        if (tid < NIN) {
            int tn = (t + 1 < SEQT) ? (t + 1) : t;
            xv = x[((size_t)b * SEQT + tn) * NIN + tid];
        }
        __syncthreads();

        float vsil = Fsil[i0 + (lane < SEGI ? lane : 0)];
        float ac0 = 0.f, ac1 = 0.f, ac2 = 0.f, ac3 = 0.f;
#define DOTP(p) { \
        float sb_lo = __uint_as_float(sbp##p << 16); \
        float sb_hi = __uint_as_float(sbp##p & 0xffff0000u); \
        float slA = __int_as_float(__builtin_amdgcn_readlane(__float_as_int(vsil), 2 * (p))); \
        float slB = __int_as_float(__builtin_amdgcn_readlane(__float_as_int(vsil), 2 * (p) + 1)); \
        uint4 bA = *(const uint4*)&Fb[i0 + 2 * (p)][0]; \
        uint4 bB = *(const uint4*)&Fb[i0 + 2 * (p) + 1][0]; \
        ac0 = __builtin_fmaf(slA, sb_lo, ac0); \
        ac0 = dot2w(bA.x, wA##p.x, ac0); ac1 = dot2w(bA.y, wA##p.y, ac1); \
        ac2 = dot2w(bA.z, wA##p.z, ac2); ac3 = dot2w(bA.w, wA##p.w, ac3); \
        ac1 = __builtin_fmaf(slB, sb_hi, ac1); \
        ac0 = dot2w(bB.x, wB##p.x, ac0); ac1 = dot2w(bB.y, wB##p.y, ac1); \
        ac2 = dot2w(bB.z, wB##p.z, ac2); ac3 = dot2w(bB.w, wB##p.w, ac3); }
        R20(DOTP)
#undef DOTP
        red[seg][o] = (ac0 + ac1) + (ac2 + ac3);
        __syncthreads();
    }

    if (tid < NHID) {
        float c = (red[0][tid] + red[1][tid]) + (red[2][tid] + red[3][tid]);
        float sil = fsilu(c);
        float b4[4]; int js;
        spline_feat(c, b4, &js);
        #pragma unroll
        for (int k = 0; k < 8; ++k) {
            int d = k - js;
            Hf[tid][k] = (d >= 0 && d < 4) ? b4[d] : 0.f;
        }
        Hf[tid][8] = sil;
    }
    __syncthreads();
    if (tid < 128) {
        int o2 = tid & 15, isg = tid >> 4;
        float acc = 0.f;
        for (int q = 0; q < 16; ++q) {
            int i = isg * 16 + q;
            const float* c2 = coef2 + (size_t)(i * NOUT + o2) * 8;
            float s = 0.f;
            #pragma unroll
            for (int k = 0; k < 8; ++k) s += Hf[i][k] * c2[k];
            acc += Hf[i][8] * sb2[i * NOUT + o2] + sp2[i * NOUT + o2] * s;
        }
        ((float*)red)[isg * 16 + o2] = acc;
    }
    __syncthreads();
    if (tid < NOUT) {
        float a = 0.f;
        #pragma unroll
        for (int g = 0; g < 8; ++g) a += ((float*)red)[g * 16 + tid];
        out[(size_t)b * NOUT + tid] = a;
    }
}

extern "C" void kernel_launch(void* const* d_in, const int* in_sizes, int n_in,
                              void* d_out, int out_size, void* d_ws, size_t ws_size,
                              hipStream_t stream) {
    const float* x     = (const float*)d_in[0];
    const float* coef1 = (const float*)d_in[1];
    const float* sb1   = (const float*)d_in[2];
    const float* sp1   = (const float*)d_in[3];
    const float* coef2 = (const float*)d_in[4];
    const float* sb2   = (const float*)d_in[5];
    const float* sp2   = (const float*)d_in[6];
    float* outp = (float*)d_out;

    // Gate on actual spill (scratch bytes), not numRegs (r8: numRegs lied).
    hipFuncAttributes attr;
    hipError_t e = hipFuncGetAttributes(&attr, reinterpret_cast<const void*>(kan_reg));
    bool use_reg = (e == hipSuccess) && (attr.localSizeBytes < 128);

    if (use_reg)
        kan_reg<<<NB, 256, 0, stream>>>(x, coef1, sb1, sp1, coef2, sb2, sp2, outp);
    else
        kan_safe<<<NB, 512, 0, stream>>>(x, coef1, sb1, sp1, coef2, sb2, sp2, outp);
}

// Round 10
// 2127.812 us; speedup vs baseline: 5.6172x; 5.6172x over previous
//
#include <hip/hip_runtime.h>
#include <hip/hip_bf16.h>

#define NIN 32
#define NHID 128
#define NOUT 16
#define NIN1 160   // NIN+NHID
#define SEQT 512
#define NB 256

// Knots: t_m = -8.8 + 1.6*m (G=5, K=3, range [-4,4]); verified rounds 3-9 PASS.
__device__ __forceinline__ void spline_feat(float c, float* out4, int* jst) {
    const float t0 = -8.8f, hh = 1.6f;
    int m0 = (int)floorf((c - t0) / hh);
    bool valid = (m0 >= 0) && (m0 <= 10);
    float v0 = 1.f, v1 = 0.f, v2 = 0.f, v3 = 0.f;
    #pragma unroll
    for (int d = 1; d <= 3; ++d) {
        float inv = 1.f / (d * hh);
        float nv[4];
        float pv[4] = {v0, v1, v2, v3};
        #pragma unroll
        for (int r = 3; r >= 0; --r) {
            if (r > d) { nv[r] = 0.f; continue; }
            int m = m0 - d + r;
            float tm = t0 + hh * (float)m;
            float left  = (r >= 1) ? pv[r-1] : 0.f;
            float right = (r <= d-1) ? pv[r] : 0.f;
            nv[r] = ((c - tm) * left + (tm + hh * (float)(d+1) - c) * right) * inv;
        }
        v0 = nv[0]; v1 = nv[1]; v2 = nv[2]; v3 = nv[3];
    }
    float v[4] = {v0, v1, v2, v3};
    int jb = m0 - 3;
    int js = jb < 0 ? 0 : (jb > 4 ? 4 : jb);
    int sh = js - jb;
    #pragma unroll
    for (int r = 0; r < 4; ++r) {
        int rs = r + sh;
        out4[r] = (valid && rs >= 0 && rs <= 3) ? v[rs] : 0.f;
    }
    *jst = js;
}

__device__ __forceinline__ float fsilu(float c) {
    return c * __builtin_amdgcn_rcpf(1.f + __expf(-c));
}

__device__ __forceinline__ unsigned RL(unsigned v, int lane) {
    return (unsigned)__builtin_amdgcn_readlane((int)v, lane);
}

// f16 helpers
typedef _Float16 h2 __attribute__((ext_vector_type(2)));
__device__ __forceinline__ unsigned pk2(float a, float b) {
    return __builtin_bit_cast(unsigned, __builtin_amdgcn_cvt_pkrtz(a, b));
}

#if defined(__has_builtin)
#if __has_builtin(__builtin_amdgcn_fdot2)
#define HAVE_FDOT2 1
#endif
#endif
#ifndef HAVE_FDOT2
#define HAVE_FDOT2 0
#endif

#if HAVE_FDOT2
__device__ __forceinline__ float dot2h(unsigned a, unsigned b, float c) {
    return __builtin_amdgcn_fdot2(__builtin_bit_cast(h2, a),
                                  __builtin_bit_cast(h2, b), c, false);
}
#else
__device__ __forceinline__ float dot2h(unsigned a, unsigned b, float c) {
    h2 ha = __builtin_bit_cast(h2, a), hb = __builtin_bit_cast(h2, b);
    return fmaf((float)ha[1], (float)hb[1], fmaf((float)ha[0], (float)hb[0], c));
}
#endif

// pool layout (uint indices); 160,576 B total -> 1 block/CU (forces 2 waves/EU
// occupancy target -> 256-VGPR grant at 256 threads, per r4-r9 allocator model)
#define PW 0        // LDS weights: 68 slots x 128 o x uint4
#define PS 34816    // LDS sb pairs: 34 x 128
#define PF 39168    // features: 2 segs x 80 rec x uint4
#define PP 39808    // silu pairs: 80 uints
#define PR 39888    // red: 2 x 128 f32
#define PTOT 40144

// feature component for record r (0..79), component c (0..3); r,c compile-time
__device__ __forceinline__ unsigned fr(uint4 vA, uint2 vB, int r, int c) {
    if (r < 64) {                    // vA: lane=record, comp=c
        unsigned x = (c == 0) ? vA.x : (c == 1) ? vA.y : (c == 2) ? vA.z : vA.w;
        return RL(x, r);
    } else {                         // vB: records 64..79, 2 uints/lane
        int f = 4 * (r - 64) + c;
        return RL((f & 1) ? vB.y : vB.x, f >> 1);
    }
}

__attribute__((amdgpu_num_vgpr(256)))
__global__ void __launch_bounds__(256)
kan_res(const float* __restrict__ x,
        const float* __restrict__ coef1,
        const float* __restrict__ sb1,
        const float* __restrict__ sp1,
        const float* __restrict__ coef2,
        const float* __restrict__ sb2,
        const float* __restrict__ sp2,
        float* __restrict__ out)
{
    __shared__ __align__(16) unsigned pool[PTOT];
    float* redf = (float*)&pool[PR];

    const int tid  = threadIdx.x;
    const int b    = blockIdx.x;
    const int o    = tid & 127;
    const int seg  = tid >> 7;           // 0..1 (wave-uniform: waves 0,1 -> seg0)
    const int lane = tid & 63;

    // ---- LDS weights: 34 i per seg (seg-records 46..79), f16, sp1 folded ----
    for (int p = tid; p < 68 * 128; p += 256) {
        int s = p >> 7, oo = p & 127;
        int sg = s >= 34, li = s - 34 * sg;
        int i = sg * 80 + 46 + li;
        const float4* cp = (const float4*)(coef1 + ((size_t)i * 128 + oo) * 8);
        float sp = sp1[i * 128 + oo];
        float4 a = cp[0], c = cp[1];
        *(uint4*)&pool[PW + p * 4] =
            make_uint4(pk2(sp * a.x, sp * a.y), pk2(sp * a.z, sp * a.w),
                       pk2(sp * c.x, sp * c.y), pk2(sp * c.z, sp * c.w));
    }
    for (int p = tid; p < 34 * 128; p += 256) {
        int q = p >> 7, oo = p & 127;
        int sg = q >= 17, qq = q - 17 * sg;
        int iA = sg * 80 + 46 + 2 * qq;
        pool[PS + p] = pk2(sb1[iA * 128 + oo], sb1[(iA + 1) * 128 + oo]);
    }

    // ---- register weights: seg-records 0..45 (23 pairs), f16, sp1 folded ----
    uint4 wreg[46];
    unsigned sbw[23];
    #pragma unroll
    for (int p = 0; p < 23; ++p) {
        int iA = seg * 80 + 2 * p;
        size_t ba = ((size_t)iA * 128 + o) * 8;
        const float4* ca = (const float4*)(coef1 + ba);
        const float4* cb = (const float4*)(coef1 + ba + 1024);
        float sA = sp1[iA * 128 + o], sB = sp1[(iA + 1) * 128 + o];
        float4 a0 = ca[0], a1 = ca[1], b0 = cb[0], b1 = cb[1];
        wreg[2 * p]     = make_uint4(pk2(sA * a0.x, sA * a0.y), pk2(sA * a0.z, sA * a0.w),
                                     pk2(sA * a1.x, sA * a1.y), pk2(sA * a1.z, sA * a1.w));
        wreg[2 * p + 1] = make_uint4(pk2(sB * b0.x, sB * b0.y), pk2(sB * b0.z, sB * b0.w),
                                     pk2(sB * b1.x, sB * b1.y), pk2(sB * b1.z, sB * b1.w));
        sbw[p] = pk2(sb1[iA * 128 + o], sb1[(iA + 1) * 128 + o]);
    }

    redf[tid] = 0.f;                      // h0 = 0 (exactly 256 floats)
    float xv = (tid < NIN) ? x[(size_t)b * SEQT * NIN + tid] : 0.f;
    __syncthreads();

    for (int t = 0; t < SEQT; ++t) {
        // ---- phase 1: f16 features (8-padded basis + silu) for 160 inputs ----
        if (tid < NIN1) {
            float c;
            if (tid < NIN) c = xv;
            else { int hi = tid - NIN; c = redf[hi] + redf[128 + hi]; }
            float sil = fsilu(c);
            float b4[4]; int js;
            spline_feat(c, b4, &js);
            float e[8];
            #pragma unroll
            for (int k = 0; k < 8; ++k) {
                int d = k - js;
                e[k] = (d >= 0 && d < 4) ? b4[d] : 0.f;
            }
            int sg = tid >= 80, r = tid - 80 * sg;
            *(uint4*)&pool[PF + sg * 320 + r * 4] =
                make_uint4(pk2(e[0], e[1]), pk2(e[2], e[3]),
                           pk2(e[4], e[5]), pk2(e[6], e[7]));
            ((unsigned short*)&pool[PP])[tid] = (unsigned short)(pk2(sil, 0.f) & 0xffffu);
        }
        if (tid < NIN) {                  // prefetch next x
            int tn = (t + 1 < SEQT) ? (t + 1) : t;
            xv = x[((size_t)b * SEQT + tn) * NIN + tid];
        }
        __syncthreads();

        // ---- phase 2: 3 LDS feature fetches/thread, readlane distribution ----
        uint4 vA = *(const uint4*)&pool[PF + seg * 320 + lane * 4];       // rec 0..63
        uint2 vB = make_uint2(0, 0);
        if (lane < 32) vB = *(const uint2*)&pool[PF + seg * 320 + 256 + lane * 2]; // 64..79
        unsigned vS = pool[PP + seg * 40 + (lane < 40 ? lane : 0)];       // silu pairs

        float ac0 = 0.f, ac1 = 0.f, ac2 = 0.f, ac3 = 0.f;
        #pragma unroll
        for (int p = 0; p < 23; ++p) {    // register weights, records 2p, 2p+1
            uint4 WA = wreg[2 * p], WB = wreg[2 * p + 1];
            ac0 = dot2h(fr(vA, vB, 2 * p, 0), WA.x, ac0);
            ac1 = dot2h(fr(vA, vB, 2 * p, 1), WA.y, ac1);
            ac2 = dot2h(fr(vA, vB, 2 * p, 2), WA.z, ac2);
            ac3 = dot2h(fr(vA, vB, 2 * p, 3), WA.w, ac3);
            ac0 = dot2h(fr(vA, vB, 2 * p + 1, 0), WB.x, ac0);
            ac1 = dot2h(fr(vA, vB, 2 * p + 1, 1), WB.y, ac1);
            ac2 = dot2h(fr(vA, vB, 2 * p + 1, 2), WB.z, ac2);
            ac3 = dot2h(fr(vA, vB, 2 * p + 1, 3), WB.w, ac3);
            ac0 = dot2h(RL(vS, p), sbw[p], ac0);
        }
        #pragma unroll
        for (int q = 0; q < 17; ++q) {    // LDS weights, records 46+2q, 47+2q
            int s0 = ((seg * 34 + 2 * q) << 7) + o;
            uint4 wa = *(const uint4*)&pool[PW + s0 * 4];
            uint4 wb = *(const uint4*)&pool[PW + s0 * 4 + 512];
            unsigned sbq = pool[PS + ((seg * 17 + q) << 7) + o];
            ac0 = dot2h(fr(vA, vB, 46 + 2 * q, 0), wa.x, ac0);
            ac1 = dot2h(fr(vA, vB, 46 + 2 * q, 1), wa.y, ac1);
            ac2 = dot2h(fr(vA, vB, 46 + 2 * q, 2), wa.z, ac2);
            ac3 = dot2h(fr(vA, vB, 46 + 2 * q, 3), wa.w, ac3);
            ac0 = dot2h(fr(vA, vB, 47 + 2 * q, 0), wb.x, ac0);
            ac1 = dot2h(fr(vA, vB, 47 + 2 * q, 1), wb.y, ac1);
            ac2 = dot2h(fr(vA, vB, 47 + 2 * q, 2), wb.z, ac2);
            ac3 = dot2h(fr(vA, vB, 47 + 2 * q, 3), wb.w, ac3);
            ac0 = dot2h(RL(vS, 23 + q), sbq, ac0);
        }
        redf[seg * 128 + o] = (ac0 + ac1) + (ac2 + ac3);
        __syncthreads();
    }

    // ---- layer 2 on final h only (fp32; verified rounds 3-9) ----
    float* Hf = (float*)pool;             // alias dead LDS-weight region: [128][9]
    if (tid < NHID) {
        float c = redf[tid] + redf[128 + tid];
        float sil = fsilu(c);
        float b4[4]; int js;
        spline_feat(c, b4, &js);
        #pragma unroll
        for (int k = 0; k < 8; ++k) {
            int d = k - js;
            Hf[tid * 9 + k] = (d >= 0 && d < 4) ? b4[d] : 0.f;
        }
        Hf[tid * 9 + 8] = sil;
    }
    __syncthreads();
    if (tid < 128) {
        int o2 = tid & 15, isg = tid >> 4;
        float acc = 0.f;
        for (int q = 0; q < 16; ++q) {
            int i = isg * 16 + q;
            const float* c2 = coef2 + (size_t)(i * NOUT + o2) * 8;
            float s = 0.f;
            #pragma unroll
            for (int k = 0; k < 8; ++k) s += Hf[i * 9 + k] * c2[k];
            acc += Hf[i * 9 + 8] * sb2[i * NOUT + o2] + sp2[i * NOUT + o2] * s;
        }
        redf[tid] = acc;
    }
    __syncthreads();
    if (tid < NOUT) {
        float a = 0.f;
        #pragma unroll
        for (int g = 0; g < 8; ++g) a += redf[g * 16 + tid];
        out[(size_t)b * NOUT + tid] = a;
    }
}

extern "C" void kernel_launch(void* const* d_in, const int* in_sizes, int n_in,
                              void* d_out, int out_size, void* d_ws, size_t ws_size,
                              hipStream_t stream) {
    kan_res<<<NB, 256, 0, stream>>>(
        (const float*)d_in[0], (const float*)d_in[1], (const float*)d_in[2],
        (const float*)d_in[3], (const float*)d_in[4], (const float*)d_in[5],
        (const float*)d_in[6], (float*)d_out);
}